// Round 14
// baseline (113.923 us; speedup 1.0000x reference)
//
#include <hip/hip_runtime.h>

typedef float f32x2 __attribute__((ext_vector_type(2)));

#define NB   2
#define SKV  1024
#define NSQ  512
#define HIN  256
#define HA   128

// projections pre-scaled by 2*log2(e):  exp2(KSC*x) = e^{2x}
// tanh(x) = 1 - 2/(e^{2x}+1); softmax is shift-invariant so the constant
// W0+bv terms of the score are dropped entirely.
#define KSC   2.8853900817779268f   // 2*log2(e)

// ---------------- Kernel A: kv projections -> exponentials ----------------
// (R2/R6 structure, kv rows ONLY — q-projection moved into attn stage-A.)
// kv rows -> ekT, INTERLEAVED-TRANSPOSED: ekT[b][a>>2][s][a&3].
__global__ __launch_bounds__(512) void proj_kernel(
    const float* __restrict__ kv,
    const float* __restrict__ Wkv,
    const float* __restrict__ bkv,
    float* __restrict__ ekT)
{
    __shared__ __align__(16) float rowf[8][HIN];
    const int t  = threadIdx.x;
    const int a  = t & 127;            // output channel
    const int rh = t >> 7;             // row-pair id (0..3)
    const int r0 = blockIdx.x * 8;     // 8 kv rows per block

    ((float4*)rowf)[t] = ((const float4*)(kv + (size_t)r0 * HIN))[t];
    __syncthreads();

    float a0 = 0.f, a1 = 0.f;
    const int ra = rh * 2, rb = rh * 2 + 1;
    #pragma unroll 4
    for (int h4 = 0; h4 < 64; ++h4) {
        const float4 r4a = ((const float4*)rowf[ra])[h4];
        const float4 r4b = ((const float4*)rowf[rb])[h4];
        #pragma unroll
        for (int j = 0; j < 4; ++j) {
            const float w = Wkv[(size_t)(h4 * 4 + j) * HA + a];
            a0 = fmaf(((const float*)&r4a)[j], w, a0);
            a1 = fmaf(((const float*)&r4b)[j], w, a1);
        }
    }
    const float bb = bkv[a];
    const float e0 = __builtin_amdgcn_exp2f((a0 + bb) * KSC);
    const float e1 = __builtin_amdgcn_exp2f((a1 + bb) * KSC);
    const int bI = r0 >> 10, s0 = r0 & 1023;
    float* __restrict__ p =
        ekT + ((size_t)(bI * 32 + (a >> 2)) * SKV + s0) * 4 + (a & 3);
    p[(size_t)ra * 4] = e0;
    p[(size_t)rb * 4] = e1;
}

// ---------------- Kernel B: q-proj + scores + softmax + weights + out ----
// one block = 4 (b,q) rows; 1024 threads (16 waves); grid 256 (1 block/CU).
// stage A: project this block's OWN 4 q rows (qy @ Wq + bq -> exp2) into
// eq_s — no eq workspace round-trip, proj_kernel is kv-only.
// phase 2: f32x2-packed pair-rcp (v_pk_fma_f32 path: 6 pk + 2 rcp slots/q
// vs 14 scalar).  Phases 3/4: R6-measured-best code, unchanged.
__global__ __launch_bounds__(1024) void attn_kernel(
    const float* __restrict__ ekT,         // (b,32,1024,4) interleaved exps
    const float* __restrict__ qy,          // (1024,256)
    const float* __restrict__ Wq,          // (256,128)
    const float* __restrict__ bq,          // (128)
    const float* __restrict__ wv,          // (128)
    const float* __restrict__ kv,          // (2048,256) f32
    float* __restrict__ out)               // [262144 out0][1048576 weights]
{
    __shared__ __align__(16) float qrow[4][HIN];       // 4 KB q-row stage
    __shared__ __align__(16) float eq_s[4][HA];        // 2 KB
    __shared__ __align__(16) float wv_s[HA];           // 0.5 KB
    __shared__ __align__(16) float wt_s[SKV][4];       // 16 KB
    __shared__ __align__(16) float part[16][4][HIN];   // 64 KB
    __shared__ float red[2][4][16];

    const int tid  = threadIdx.x;
    const int lane = tid & 63, wid = tid >> 6;
    const int bq0  = blockIdx.x * 4;       // never straddles b (512%4==0)
    const int b    = bq0 >> 9;

    // ---- stage A: load 4 qy rows + wv; project q rows into eq_s ----
    if (tid < 256)      ((float4*)qrow)[tid] = ((const float4*)(qy + (size_t)bq0 * HIN))[tid];
    else if (tid < 384) wv_s[tid - 256]      = wv[tid - 256];
    __syncthreads();
    if (tid < 512) {
        const int qq = tid >> 7, a = tid & 127;
        const float* __restrict__ row = qrow[qq];
        float acc = 0.f;
        #pragma unroll 4
        for (int h4 = 0; h4 < 64; ++h4) {
            const float4 r = ((const float4*)row)[h4];         // LDS broadcast
            acc = fmaf(r.x, Wq[(size_t)(h4 * 4 + 0) * HA + a], acc);
            acc = fmaf(r.y, Wq[(size_t)(h4 * 4 + 1) * HA + a], acc);
            acc = fmaf(r.z, Wq[(size_t)(h4 * 4 + 2) * HA + a], acc);
            acc = fmaf(r.w, Wq[(size_t)(h4 * 4 + 3) * HA + a], acc);
        }
        eq_s[qq][a] = __builtin_amdgcn_exp2f((acc + bq[a]) * KSC);
    }
    __syncthreads();

    // ---- phase 2: per-thread s = tid; packed pair-rcp over a ----
    const float4* __restrict__ E4 =
        (const float4*)ekT + (size_t)b * 32 * SKV + tid;   // + a4*SKV per iter
    f32x2 t0 = {0.f, 0.f}, t1 = {0.f, 0.f}, t2 = {0.f, 0.f}, t3 = {0.f, 0.f};
    const f32x2 one2 = {1.f, 1.f};

    #pragma unroll 4
    for (int a4 = 0; a4 < 32; ++a4) {
        const float4 E = E4[(size_t)a4 * SKV];             // coalesced b128
        const float4 w = ((const float4*)wv_s)[a4];        // LDS broadcast
        const f32x2 Exy = {E.x, E.y}, Ezw = {E.z, E.w};
        const f32x2 wxz = {w.x, w.z}, wyw = {w.y, w.w};

#define PQ(ACC, QI)                                                           \
        {                                                                     \
            const float4 Q = ((const float4*)eq_s[QI])[a4];  /* broadcast */  \
            const f32x2 U1 = __builtin_elementwise_fma(Exy,                   \
                                 (f32x2){Q.x, Q.y}, one2);   /* {u1,v1} */    \
            const f32x2 U2 = __builtin_elementwise_fma(Ezw,                   \
                                 (f32x2){Q.z, Q.w}, one2);   /* {u2,v2} */    \
            const f32x2 Uu = {U1.x, U2.x}, Uv = {U1.y, U2.y};                 \
            const f32x2 N  = __builtin_elementwise_fma(wxz, Uv, wyw * Uu);    \
            const f32x2 D  = Uu * Uv;                                         \
            f32x2 R;                                                          \
            R.x = __builtin_amdgcn_rcpf(D.x);                                 \
            R.y = __builtin_amdgcn_rcpf(D.y);                                 \
            ACC = __builtin_elementwise_fma(N, R, ACC);                       \
        }
        PQ(t0, 0) PQ(t1, 1) PQ(t2, 2) PQ(t3, 3)
#undef PQ
    }

    // ---- phase 3: softmax over s.  weight ∝ exp(-2*(t - tmin)) ----
    float tq[4] = {t0.x + t0.y, t1.x + t1.y, t2.x + t2.y, t3.x + t3.y};
    #pragma unroll
    for (int q = 0; q < 4; ++q) {
        float m = tq[q];
        #pragma unroll
        for (int o = 32; o > 0; o >>= 1) m = fminf(m, __shfl_down(m, o));
        if (lane == 0) red[0][q][wid] = m;
    }
    __syncthreads();
    float M[4];
    #pragma unroll
    for (int q = 0; q < 4; ++q) {
        float m = red[0][q][0];
        #pragma unroll
        for (int i = 1; i < 16; ++i) m = fminf(m, red[0][q][i]);
        M[q] = m;
    }
    float e[4];
    #pragma unroll
    for (int q = 0; q < 4; ++q) {
        e[q] = __builtin_amdgcn_exp2f((M[q] - tq[q]) * KSC);   // exp(-2(t-tmin))
        float sum = e[q];
        #pragma unroll
        for (int o = 32; o > 0; o >>= 1) sum += __shfl_down(sum, o);
        if (lane == 0) red[1][q][wid] = sum;
    }
    __syncthreads();
    float* __restrict__ outw = out + (size_t)NB * NSQ * HIN;   // weights at 262144
    float wgt[4];
    #pragma unroll
    for (int q = 0; q < 4; ++q) {
        float d = red[1][q][0];
        #pragma unroll
        for (int i = 1; i < 16; ++i) d += red[1][q][i];
        wgt[q] = e[q] * __builtin_amdgcn_rcpf(d);
        outw[(size_t)(bq0 + q) * SKV + tid] = wgt[q];          // coalesced per q
    }
    *(float4*)&wt_s[tid][0] = make_float4(wgt[0], wgt[1], wgt[2], wgt[3]);
    __syncthreads();

    // ---- phase 4: out[q][h] = sum_s w[q][s]*kv[b][s][h] ----
    {
        const int g = wid;                 // 0..15, s in [g*64, g*64+64)
        float4 ac0 = {0,0,0,0}, ac1 = {0,0,0,0}, ac2 = {0,0,0,0}, ac3 = {0,0,0,0};
        const float4* __restrict__ kvb =
            (const float4*)kv + (size_t)(b * SKV + g * 64) * 64;
        #pragma unroll 4
        for (int i = 0; i < 64; ++i) {
            const float4 w4 = *((const float4*)&wt_s[g * 64 + i][0]); // broadcast
            const float4 v  = kvb[(size_t)i * 64 + lane];             // 1KB/wave
            ac0.x = fmaf(w4.x, v.x, ac0.x); ac0.y = fmaf(w4.x, v.y, ac0.y);
            ac0.z = fmaf(w4.x, v.z, ac0.z); ac0.w = fmaf(w4.x, v.w, ac0.w);
            ac1.x = fmaf(w4.y, v.x, ac1.x); ac1.y = fmaf(w4.y, v.y, ac1.y);
            ac1.z = fmaf(w4.y, v.z, ac1.z); ac1.w = fmaf(w4.y, v.w, ac1.w);
            ac2.x = fmaf(w4.z, v.x, ac2.x); ac2.y = fmaf(w4.z, v.y, ac2.y);
            ac2.z = fmaf(w4.z, v.z, ac2.z); ac2.w = fmaf(w4.z, v.w, ac2.w);
            ac3.x = fmaf(w4.w, v.x, ac3.x); ac3.y = fmaf(w4.w, v.y, ac3.y);
            ac3.z = fmaf(w4.w, v.z, ac3.z); ac3.w = fmaf(w4.w, v.w, ac3.w);
        }
        ((float4*)part[g][0])[lane] = ac0;
        ((float4*)part[g][1])[lane] = ac1;
        ((float4*)part[g][2])[lane] = ac2;
        ((float4*)part[g][3])[lane] = ac3;
    }
    __syncthreads();
    {
        const int q = tid >> 8, h = tid & 255;       // 1024 outputs, 1/thread
        float v = 0.f;
        #pragma unroll
        for (int g2 = 0; g2 < 16; ++g2) v += part[g2][q][h];   // stride-1 banks
        out[(size_t)(bq0 + q) * HIN + h] = v;        // coalesced
    }
}

extern "C" void kernel_launch(void* const* d_in, const int* in_sizes, int n_in,
                              void* d_out, int out_size, void* d_ws, size_t ws_size,
                              hipStream_t stream) {
    (void)in_sizes; (void)n_in; (void)out_size; (void)ws_size;
    const float* kv  = (const float*)d_in[0];
    const float* qy  = (const float*)d_in[1];
    const float* Wkv = (const float*)d_in[2];
    const float* bkv = (const float*)d_in[3];
    const float* Wq  = (const float*)d_in[4];
    const float* bq  = (const float*)d_in[5];
    const float* wv  = (const float*)d_in[6];
    float* ekT = (float*)d_ws;                 // 1 MB
    float* out = (float*)d_out;

    hipLaunchKernelGGL(proj_kernel, dim3(NB * SKV / 8), dim3(512), 0, stream,
                       kv, Wkv, bkv, ekT);
    hipLaunchKernelGGL(attn_kernel, dim3(NB * NSQ / 4), dim3(1024), 0, stream,
                       ekT, qy, Wq, bq, wv, kv, out);
}